// Round 1
// baseline (658.718 us; speedup 1.0000x reference)
//
#include <hip/hip_runtime.h>
#include <math.h>

// ---------------------------------------------------------------------------
// GATv2 (2 layers) forward on MI355X.
// Inputs (f32 unless noted):
//  0 x [N,512], 1 edge_index int32 [2,E], 2 W1l[512,128], 3 b1l[128],
//  4 W1r[512,128], 5 b1r[128], 6 a1[128], 7 bias1[128],
//  8 W2l[128,40], 9 b2l[40], 10 W2r[128,40], 11 b2r[40], 12 a2[40], 13 bias2[40]
// Output: h2 [N,40] then log_softmax(h2) [N,40], concatenated.
// ---------------------------------------------------------------------------

#define FIN 512
#define H1 128
#define C2 40

// ---------------- CSR build ----------------
__global__ void count_k(const int* __restrict__ dst, int* __restrict__ cnt, int E) {
    int e = blockIdx.x * 256 + threadIdx.x;
    if (e < E) atomicAdd(&cnt[dst[e] + 1], 1);
}

__global__ __launch_bounds__(1024) void scan_k(int* __restrict__ arr, int ntot) {
    __shared__ int part[1024];
    int t = threadIdx.x;
    int chunk = (ntot + 1023) / 1024;
    int b = t * chunk;
    int e = b + chunk; if (e > ntot) e = ntot;
    int s = 0;
    for (int j = b; j < e; j++) s += arr[j];
    part[t] = s;
    __syncthreads();
    for (int off = 1; off < 1024; off <<= 1) {
        int v = (t >= off) ? part[t - off] : 0;
        __syncthreads();
        part[t] += v;
        __syncthreads();
    }
    int run = (t == 0) ? 0 : part[t - 1];
    for (int j = b; j < e; j++) { run += arr[j]; arr[j] = run; }
}

__global__ void fill_k(const int* __restrict__ src, const int* __restrict__ dst,
                       const int* __restrict__ rowptr, int* __restrict__ fillp,
                       int* __restrict__ csr, int E) {
    int e = blockIdx.x * 256 + threadIdx.x;
    if (e < E) {
        int d = dst[e];
        int p = atomicAdd(&fillp[d], 1);
        csr[rowptr[d] + p] = src[e];
    }
}

// ---------------- GEMM1: x[N,512] @ {W1l,W1r}[512,128] + b -> xl1,xr1 ----------------
// Block: 256 threads, tile 64 rows x 128 cols, 8x4 microtile.
__global__ __launch_bounds__(256) void gemm1_k(
    const float* __restrict__ x,
    const float* __restrict__ Wl, const float* __restrict__ bl,
    const float* __restrict__ Wr, const float* __restrict__ br,
    float* __restrict__ xl, float* __restrict__ xr, int n)
{
    __shared__ float As[32][68];   // A^T tile (k, row), padded
    __shared__ float Bs[32][128];  // B tile (k, col)

    const int which = blockIdx.x & 1;
    const int r0 = (blockIdx.x >> 1) * 64;
    const float* W    = which ? Wr : Wl;
    const float* bias = which ? br : bl;
    float* out        = which ? xr : xl;

    const int tid  = threadIdx.x;
    const int colg = tid & 31;   // cols colg*4 .. +3
    const int rowg = tid >> 5;   // rows rowg*8 .. +7

    float acc[8][4];
#pragma unroll
    for (int r = 0; r < 8; r++)
#pragma unroll
        for (int c = 0; c < 4; c++) acc[r][c] = 0.f;

    const int tr = tid >> 3;          // 0..31
    const int tk = (tid & 7) * 4;     // 0..28
    const int tc = (tid & 31) * 4;    // 0..124
    const int tkB = tid >> 5;         // 0..7

    for (int kk = 0; kk < FIN; kk += 32) {
        // stage A^T (64 rows x 32 k)
#pragma unroll
        for (int p = 0; p < 2; p++) {
            int row = r0 + tr + p * 32;
            int rowc = row < n ? row : n - 1;
            float4 v = *reinterpret_cast<const float4*>(&x[(size_t)rowc * FIN + kk + tk]);
            As[tk + 0][tr + p * 32] = v.x;
            As[tk + 1][tr + p * 32] = v.y;
            As[tk + 2][tr + p * 32] = v.z;
            As[tk + 3][tr + p * 32] = v.w;
        }
        // stage B (32 k x 128 cols)
#pragma unroll
        for (int p = 0; p < 4; p++) {
            int k = tkB + p * 8;
            *reinterpret_cast<float4*>(&Bs[k][tc]) =
                *reinterpret_cast<const float4*>(&W[(size_t)(kk + k) * H1 + tc]);
        }
        __syncthreads();
#pragma unroll
        for (int k = 0; k < 32; k++) {
            float4 a0 = *reinterpret_cast<const float4*>(&As[k][rowg * 8]);
            float4 a1 = *reinterpret_cast<const float4*>(&As[k][rowg * 8 + 4]);
            float4 bv = *reinterpret_cast<const float4*>(&Bs[k][colg * 4]);
            float a[8] = {a0.x, a0.y, a0.z, a0.w, a1.x, a1.y, a1.z, a1.w};
            float b[4] = {bv.x, bv.y, bv.z, bv.w};
#pragma unroll
            for (int r = 0; r < 8; r++)
#pragma unroll
                for (int c = 0; c < 4; c++) acc[r][c] += a[r] * b[c];
        }
        __syncthreads();
    }

    float bv[4];
#pragma unroll
    for (int c = 0; c < 4; c++) bv[c] = bias[colg * 4 + c];
#pragma unroll
    for (int r = 0; r < 8; r++) {
        int row = r0 + rowg * 8 + r;
        if (row < n) {
            float4 o;
            o.x = acc[r][0] + bv[0];
            o.y = acc[r][1] + bv[1];
            o.z = acc[r][2] + bv[2];
            o.w = acc[r][3] + bv[3];
            *reinterpret_cast<float4*>(&out[(size_t)row * H1 + colg * 4]) = o;
        }
    }
}

// ---------------- Edge layer 1: per-dst wave, online softmax, fused bias+ELU ----------------
// h may alias xr (no restrict on those).
__global__ __launch_bounds__(256) void edge1_k(
    const float* __restrict__ xl, const float* xr,
    const int* __restrict__ rowptr, const int* __restrict__ csr,
    const float* __restrict__ att, const float* __restrict__ bias,
    float* h, int n)
{
    int wid  = threadIdx.x >> 6;
    int lane = threadIdx.x & 63;
    int i = blockIdx.x * 4 + wid;
    if (i >= n) return;

    float2 xrv = *reinterpret_cast<const float2*>(&xr[(size_t)i * H1 + lane * 2]);
    float2 av  = *reinterpret_cast<const float2*>(&att[lane * 2]);
    int e0 = rowptr[i], e1 = rowptr[i + 1];

    float m = -INFINITY, den = 0.f, acc0 = 0.f, acc1 = 0.f;
    for (int e = e0; e < e1; e++) {
        int s = csr[e];
        float2 xlv = *reinterpret_cast<const float2*>(&xl[(size_t)s * H1 + lane * 2]);
        float t0 = xlv.x + xrv.x; t0 = t0 > 0.f ? t0 : 0.2f * t0;
        float t1 = xlv.y + xrv.y; t1 = t1 > 0.f ? t1 : 0.2f * t1;
        float p = t0 * av.x + t1 * av.y;
#pragma unroll
        for (int o = 32; o > 0; o >>= 1) p += __shfl_xor(p, o);
        float mn = fmaxf(m, p);
        float sc = __expf(m - mn);
        float w  = __expf(p - mn);
        den  = den  * sc + w;
        acc0 = acc0 * sc + w * xlv.x;
        acc1 = acc1 * sc + w * xlv.y;
        m = mn;
    }
    float inv = 1.f / den;
    float o0 = acc0 * inv + bias[lane * 2];
    float o1 = acc1 * inv + bias[lane * 2 + 1];
    o0 = o0 > 0.f ? o0 : expm1f(o0);   // ELU(alpha=1)
    o1 = o1 > 0.f ? o1 : expm1f(o1);
    *reinterpret_cast<float2*>(&h[(size_t)i * H1 + lane * 2]) = make_float2(o0, o1);
}

// ---------------- GEMM2: h[N,128] @ {W2l,W2r}[128,40] + b -> xl2,xr2 ----------------
__global__ __launch_bounds__(320) void gemm2_k(
    const float* __restrict__ h,
    const float* __restrict__ Wl, const float* __restrict__ bl,
    const float* __restrict__ Wr, const float* __restrict__ br,
    float* __restrict__ xl, float* __restrict__ xr, int n)
{
    __shared__ float hs[4 * H1];
    int r0 = blockIdx.x * 4;
    for (int j = threadIdx.x; j < 4 * H1; j += 320) {
        int row = r0 + (j >> 7);
        hs[j] = row < n ? h[(size_t)row * H1 + (j & 127)] : 0.f;
    }
    __syncthreads();
    int r = threadIdx.x / 80;
    int c = threadIdx.x % 80;
    const float* W = (c < C2) ? Wl : Wr;
    int cc = (c < C2) ? c : c - C2;
    float acc = 0.f;
#pragma unroll 4
    for (int k = 0; k < H1; k++) acc += hs[r * H1 + k] * W[k * C2 + cc];
    int row = r0 + r;
    if (row < n) {
        float b = (c < C2) ? bl[cc] : br[cc];
        float* dstp = (c < C2) ? xl : xr;
        dstp[(size_t)row * C2 + cc] = acc + b;
    }
}

// ---------------- Edge layer 2 + bias + log_softmax, fused final output ----------------
__global__ __launch_bounds__(256) void edge2_k(
    const float* __restrict__ xl, const float* __restrict__ xr,
    const int* __restrict__ rowptr, const int* __restrict__ csr,
    const float* __restrict__ att, const float* __restrict__ bias,
    float* __restrict__ out, int n)
{
    int wid  = threadIdx.x >> 6;
    int lane = threadIdx.x & 63;
    int i = blockIdx.x * 4 + wid;
    if (i >= n) return;
    bool act = lane < C2;

    float xrv = act ? xr[(size_t)i * C2 + lane] : 0.f;
    float av  = act ? att[lane] : 0.f;
    int e0 = rowptr[i], e1 = rowptr[i + 1];

    float m = -INFINITY, den = 0.f, acc = 0.f;
    for (int e = e0; e < e1; e++) {
        int s = csr[e];
        float xlv = act ? xl[(size_t)s * C2 + lane] : 0.f;
        float t = xlv + xrv; t = t > 0.f ? t : 0.2f * t;
        float p = t * av;
#pragma unroll
        for (int o = 32; o > 0; o >>= 1) p += __shfl_xor(p, o);
        float mn = fmaxf(m, p);
        float sc = __expf(m - mn);
        float w  = __expf(p - mn);
        den = den * sc + w;
        acc = acc * sc + w * xlv;
        m = mn;
    }
    float o = acc / den + (act ? bias[lane] : 0.f);
    if (act) out[(size_t)i * C2 + lane] = o;

    // log-softmax over the 40 classes of this row
    float mv = act ? o : -INFINITY;
#pragma unroll
    for (int off = 32; off > 0; off >>= 1) mv = fmaxf(mv, __shfl_xor(mv, off));
    float ex = act ? __expf(o - mv) : 0.f;
    float se = ex;
#pragma unroll
    for (int off = 32; off > 0; off >>= 1) se += __shfl_xor(se, off);
    float lse = mv + logf(se);
    if (act) out[(size_t)n * C2 + (size_t)i * C2 + lane] = o - lse;
}

// ---------------------------------------------------------------------------
extern "C" void kernel_launch(void* const* d_in, const int* in_sizes, int n_in,
                              void* d_out, int out_size, void* d_ws, size_t ws_size,
                              hipStream_t stream) {
    const float* x    = (const float*)d_in[0];
    const int*   ei   = (const int*)  d_in[1];
    const float* W1l  = (const float*)d_in[2];
    const float* b1l  = (const float*)d_in[3];
    const float* W1r  = (const float*)d_in[4];
    const float* b1r  = (const float*)d_in[5];
    const float* a1   = (const float*)d_in[6];
    const float* bias1= (const float*)d_in[7];
    const float* W2l  = (const float*)d_in[8];
    const float* b2l  = (const float*)d_in[9];
    const float* W2r  = (const float*)d_in[10];
    const float* b2r  = (const float*)d_in[11];
    const float* a2   = (const float*)d_in[12];
    const float* bias2= (const float*)d_in[13];

    const int N = in_sizes[0] / FIN;
    const int E = in_sizes[1] / 2;
    const int* src = ei;
    const int* dst = ei + E;

    // workspace layout
    float* xl1 = (float*)d_ws;                    // N*128
    float* xr1 = xl1 + (size_t)N * H1;            // N*128 (also reused as h)
    float* xl2 = xr1 + (size_t)N * H1;            // N*40
    float* xr2 = xl2 + (size_t)N * C2;            // N*40
    int* rowptr = (int*)(xr2 + (size_t)N * C2);   // N+1
    int* fillp  = rowptr + (N + 1);               // N
    int* csr    = fillp + N;                      // E

    hipMemsetAsync(rowptr, 0, sizeof(int) * (size_t)(2 * N + 1), stream);
    count_k<<<(E + 255) / 256, 256, 0, stream>>>(dst, rowptr, E);
    scan_k<<<1, 1024, 0, stream>>>(rowptr, N + 1);
    fill_k<<<(E + 255) / 256, 256, 0, stream>>>(src, dst, rowptr, fillp, csr, E);

    gemm1_k<<<((N + 63) / 64) * 2, 256, 0, stream>>>(x, W1l, b1l, W1r, b1r, xl1, xr1, N);
    edge1_k<<<(N + 3) / 4, 256, 0, stream>>>(xl1, xr1, rowptr, csr, a1, bias1, /*h=*/xr1, N);
    gemm2_k<<<(N + 3) / 4, 320, 0, stream>>>(xr1, W2l, b2l, W2r, b2r, xl2, xr2, N);
    edge2_k<<<(N + 3) / 4, 256, 0, stream>>>(xl2, xr2, rowptr, csr, a2, bias2, (float*)d_out, N);
}

// Round 2
// 513.321 us; speedup vs baseline: 1.2832x; 1.2832x over previous
//
#include <hip/hip_runtime.h>
#include <math.h>

#define FIN 512
#define H1 128
#define C2 40

typedef __attribute__((ext_vector_type(8))) short short8;
typedef __attribute__((ext_vector_type(4))) float f32x4;

__device__ __forceinline__ ushort f2bf(float f) {
    union { float f; unsigned u; } c; c.f = f;
    unsigned u = c.u;
    return (ushort)((u + 0x7fffu + ((u >> 16) & 1u)) >> 16);   // RNE
}

// ---------------- CSR build ----------------
__global__ void count_k(const int* __restrict__ dst, int* __restrict__ cnt, int E) {
    int e = blockIdx.x * 256 + threadIdx.x;
    if (e < E) atomicAdd(&cnt[dst[e] + 1], 1);
}

__global__ __launch_bounds__(1024) void scan_k(int* __restrict__ arr, int ntot) {
    __shared__ int part[1024];
    int t = threadIdx.x;
    int chunk = (ntot + 1023) / 1024;
    int b = t * chunk;
    int e = b + chunk; if (e > ntot) e = ntot;
    int s = 0;
    for (int j = b; j < e; j++) s += arr[j];
    part[t] = s;
    __syncthreads();
    for (int off = 1; off < 1024; off <<= 1) {
        int v = (t >= off) ? part[t - off] : 0;
        __syncthreads();
        part[t] += v;
        __syncthreads();
    }
    int run = (t == 0) ? 0 : part[t - 1];
    for (int j = b; j < e; j++) { run += arr[j]; arr[j] = run; }
}

__global__ void fill_k(const int* __restrict__ src, const int* __restrict__ dst,
                       const int* __restrict__ rowptr, int* __restrict__ fillp,
                       int* __restrict__ csr, int E) {
    int e = blockIdx.x * 256 + threadIdx.x;
    if (e < E) {
        int d = dst[e];
        int p = atomicAdd(&fillp[d], 1);
        csr[rowptr[d] + p] = src[e];
    }
}

// ---------------- W1 preconvert: Wt2[kc][col][j] = bf16(W[kc*8+j][col]) ----------------
// kc in [0,64), col in [0,256) (0-127 = W1l, 128-255 = W1r), j in [0,8)
__global__ void prep_k(const float* __restrict__ W1l, const float* __restrict__ W1r,
                       ushort* __restrict__ Wt2) {
    int idx = blockIdx.x * 256 + threadIdx.x;   // 64*256*8 = 131072
    int kc  = idx >> 11;
    int rem = idx & 2047;
    int col = rem >> 3;
    int j   = rem & 7;
    int k   = kc * 8 + j;
    float v = (col < H1) ? W1l[k * H1 + col] : W1r[k * H1 + (col - H1)];
    Wt2[idx] = f2bf(v);
}

// ---------------- GEMM1 (MFMA bf16): x[N,512] @ [W1l|W1r] -> xlb (bf16), xr (f32) ----------
// 256 threads = 4 waves; block tile 64 x 256; wave tile 64 x 64; 4x4 frags of 16x16.
__global__ __launch_bounds__(256) void gemm1_k(
    const float* __restrict__ x, const ushort* __restrict__ Wt2,
    const float* __restrict__ bl, const float* __restrict__ br,
    ushort* __restrict__ xlb, float* __restrict__ xr, int n)
{
    __shared__ ushort As[64][40];    // [row][k], +8 pad -> 80B stride (2-way max)
    __shared__ ushort Bs[256][36];   // [col][k], +4 pad -> 72B stride (<=4-way)

    const int tid = threadIdx.x;
    const int r0  = blockIdx.x * 64;
    const int w    = tid >> 6;
    const int lane = tid & 63;
    const int l15  = lane & 15;
    const int lhi  = lane >> 4;

    f32x4 acc[4][4];
#pragma unroll
    for (int m = 0; m < 4; m++)
#pragma unroll
        for (int nn = 0; nn < 4; nn++) acc[m][nn] = (f32x4){0.f, 0.f, 0.f, 0.f};

    const int arow = tid >> 2;
    const int akc  = (tid & 3) * 8;
    const int arow_g = min(r0 + arow, n - 1);
    const float* aptr = x + (size_t)arow_g * FIN + akc;

    for (int kk = 0; kk < FIN; kk += 32) {
        // stage A: 64 rows x 32 k, fp32 -> bf16
        float4 v0 = *reinterpret_cast<const float4*>(aptr + kk);
        float4 v1 = *reinterpret_cast<const float4*>(aptr + kk + 4);
        short8 ah;
        ah[0] = (short)f2bf(v0.x); ah[1] = (short)f2bf(v0.y);
        ah[2] = (short)f2bf(v0.z); ah[3] = (short)f2bf(v0.w);
        ah[4] = (short)f2bf(v1.x); ah[5] = (short)f2bf(v1.y);
        ah[6] = (short)f2bf(v1.z); ah[7] = (short)f2bf(v1.w);
        *reinterpret_cast<short8*>(&As[arow][akc]) = ah;

        // stage B: 256 cols x 32 k from pre-converted k-chunked layout (coalesced 16B)
        int kc0 = kk >> 3;
#pragma unroll
        for (int q = 0; q < 4; q++) {
            short8 bh = *reinterpret_cast<const short8*>(&Wt2[(size_t)((kc0 + q) * 256 + tid) * 8]);
            *reinterpret_cast<short8*>(&Bs[tid][q * 8]) = bh;
        }
        __syncthreads();

        short8 af[4], bfr[4];
#pragma unroll
        for (int m = 0; m < 4; m++)
            af[m] = *reinterpret_cast<const short8*>(&As[m * 16 + l15][lhi * 8]);
#pragma unroll
        for (int nn = 0; nn < 4; nn++)
            bfr[nn] = *reinterpret_cast<const short8*>(&Bs[w * 64 + nn * 16 + l15][lhi * 8]);
#pragma unroll
        for (int m = 0; m < 4; m++)
#pragma unroll
            for (int nn = 0; nn < 4; nn++)
                acc[m][nn] = __builtin_amdgcn_mfma_f32_16x16x32_bf16(af[m], bfr[nn], acc[m][nn], 0, 0, 0);
        __syncthreads();
    }

    // epilogue: C/D layout col = lane&15, row = (lane>>4)*4 + r  [m89]
#pragma unroll
    for (int nn = 0; nn < 4; nn++) {
        int col = w * 64 + nn * 16 + l15;
        bool left = (col < H1);                       // wave-uniform (w<2)
        float bias = left ? bl[col] : br[col - H1];
#pragma unroll
        for (int m = 0; m < 4; m++) {
#pragma unroll
            for (int r = 0; r < 4; r++) {
                int row = r0 + m * 16 + lhi * 4 + r;
                if (row < n) {
                    float v = acc[m][nn][r] + bias;
                    if (left) xlb[(size_t)row * H1 + col] = f2bf(v);
                    else      xr [(size_t)row * H1 + (col - H1)] = v;
                }
            }
        }
    }
}

// ---------------- Edge layer 1: per-dst wave, online softmax, fused bias+ELU ----------------
__global__ __launch_bounds__(256) void edge1_k(
    const ushort* __restrict__ xlb, const float* xr,
    const int* __restrict__ rowptr, const int* __restrict__ csr,
    const float* __restrict__ att, const float* __restrict__ bias,
    float* h, int n)
{
    int wid  = threadIdx.x >> 6;
    int lane = threadIdx.x & 63;
    int i = blockIdx.x * 4 + wid;
    if (i >= n) return;

    float2 xrv = *reinterpret_cast<const float2*>(&xr[(size_t)i * H1 + lane * 2]);
    float2 av  = *reinterpret_cast<const float2*>(&att[lane * 2]);
    int e0 = rowptr[i], e1 = rowptr[i + 1];

    int s = csr[e0];
    unsigned u = *reinterpret_cast<const unsigned*>(&xlb[(size_t)s * H1 + lane * 2]);

    float m = -INFINITY, den = 0.f, acc0 = 0.f, acc1 = 0.f;
    for (int e = e0; e < e1; e++) {
        float xl0 = __uint_as_float(u << 16);
        float xl1 = __uint_as_float(u & 0xffff0000u);
        if (e + 1 < e1) {     // prefetch next gather before the reduce chain
            int s2 = csr[e + 1];
            u = *reinterpret_cast<const unsigned*>(&xlb[(size_t)s2 * H1 + lane * 2]);
        }
        float t0 = xl0 + xrv.x; t0 = t0 > 0.f ? t0 : 0.2f * t0;
        float t1 = xl1 + xrv.y; t1 = t1 > 0.f ? t1 : 0.2f * t1;
        float p = t0 * av.x + t1 * av.y;
#pragma unroll
        for (int o = 32; o > 0; o >>= 1) p += __shfl_xor(p, o);
        float mn = fmaxf(m, p);
        float sc = __expf(m - mn);
        float wgt = __expf(p - mn);
        den  = den  * sc + wgt;
        acc0 = acc0 * sc + wgt * xl0;
        acc1 = acc1 * sc + wgt * xl1;
        m = mn;
    }
    float inv = 1.f / den;
    float o0 = acc0 * inv + bias[lane * 2];
    float o1 = acc1 * inv + bias[lane * 2 + 1];
    o0 = o0 > 0.f ? o0 : expm1f(o0);   // ELU
    o1 = o1 > 0.f ? o1 : expm1f(o1);
    *reinterpret_cast<float2*>(&h[(size_t)i * H1 + lane * 2]) = make_float2(o0, o1);
}

// ---------------- GEMM2: h[N,128] @ {W2l,W2r}[128,40] + b -> xl2,xr2 ----------------
__global__ __launch_bounds__(320) void gemm2_k(
    const float* __restrict__ h,
    const float* __restrict__ Wl, const float* __restrict__ bl,
    const float* __restrict__ Wr, const float* __restrict__ br,
    float* __restrict__ xl, float* __restrict__ xr, int n)
{
    __shared__ float hs[4 * H1];
    int r0 = blockIdx.x * 4;
    for (int j = threadIdx.x; j < 4 * H1; j += 320) {
        int row = r0 + (j >> 7);
        hs[j] = row < n ? h[(size_t)row * H1 + (j & 127)] : 0.f;
    }
    __syncthreads();
    int r = threadIdx.x / 80;
    int c = threadIdx.x % 80;
    const float* W = (c < C2) ? Wl : Wr;
    int cc = (c < C2) ? c : c - C2;
    float acc = 0.f;
#pragma unroll 4
    for (int k = 0; k < H1; k++) acc += hs[r * H1 + k] * W[k * C2 + cc];
    int row = r0 + r;
    if (row < n) {
        float b = (c < C2) ? bl[cc] : br[cc];
        float* dstp = (c < C2) ? xl : xr;
        dstp[(size_t)row * C2 + cc] = acc + b;
    }
}

// ---------------- Edge layer 2 + bias + log_softmax, fused final output ----------------
__global__ __launch_bounds__(256) void edge2_k(
    const float* __restrict__ xl, const float* __restrict__ xr,
    const int* __restrict__ rowptr, const int* __restrict__ csr,
    const float* __restrict__ att, const float* __restrict__ bias,
    float* __restrict__ out, int n)
{
    int wid  = threadIdx.x >> 6;
    int lane = threadIdx.x & 63;
    int i = blockIdx.x * 4 + wid;
    if (i >= n) return;
    bool act = lane < C2;

    float xrv = act ? xr[(size_t)i * C2 + lane] : 0.f;
    float av  = act ? att[lane] : 0.f;
    int e0 = rowptr[i], e1 = rowptr[i + 1];

    int s = csr[e0];
    float xlv = act ? xl[(size_t)s * C2 + lane] : 0.f;

    float m = -INFINITY, den = 0.f, acc = 0.f;
    for (int e = e0; e < e1; e++) {
        float cur = xlv;
        if (e + 1 < e1) {
            int s2 = csr[e + 1];
            xlv = act ? xl[(size_t)s2 * C2 + lane] : 0.f;
        }
        float t = cur + xrv; t = t > 0.f ? t : 0.2f * t;
        float p = t * av;
#pragma unroll
        for (int o = 32; o > 0; o >>= 1) p += __shfl_xor(p, o);
        float mn = fmaxf(m, p);
        float sc = __expf(m - mn);
        float wgt = __expf(p - mn);
        den = den * sc + wgt;
        acc = acc * sc + wgt * cur;
        m = mn;
    }
    float o = acc / den + (act ? bias[lane] : 0.f);
    if (act) out[(size_t)i * C2 + lane] = o;

    float mv = act ? o : -INFINITY;
#pragma unroll
    for (int off = 32; off > 0; off >>= 1) mv = fmaxf(mv, __shfl_xor(mv, off));
    float ex = act ? __expf(o - mv) : 0.f;
    float se = ex;
#pragma unroll
    for (int off = 32; off > 0; off >>= 1) se += __shfl_xor(se, off);
    float lse = mv + logf(se);
    if (act) out[(size_t)n * C2 + (size_t)i * C2 + lane] = o - lse;
}

// ---------------------------------------------------------------------------
extern "C" void kernel_launch(void* const* d_in, const int* in_sizes, int n_in,
                              void* d_out, int out_size, void* d_ws, size_t ws_size,
                              hipStream_t stream) {
    const float* x    = (const float*)d_in[0];
    const int*   ei   = (const int*)  d_in[1];
    const float* W1l  = (const float*)d_in[2];
    const float* b1l  = (const float*)d_in[3];
    const float* W1r  = (const float*)d_in[4];
    const float* b1r  = (const float*)d_in[5];
    const float* a1   = (const float*)d_in[6];
    const float* bias1= (const float*)d_in[7];
    const float* W2l  = (const float*)d_in[8];
    const float* b2l  = (const float*)d_in[9];
    const float* W2r  = (const float*)d_in[10];
    const float* b2r  = (const float*)d_in[11];
    const float* a2   = (const float*)d_in[12];
    const float* bias2= (const float*)d_in[13];

    const int N = in_sizes[0] / FIN;
    const int E = in_sizes[1] / 2;
    const int* src = ei;
    const int* dst = ei + E;

    // workspace layout
    float*  xr1 = (float*)d_ws;                       // N*128 f32 (h aliases after edge1)
    float*  xl2 = xr1 + (size_t)N * H1;               // N*40
    float*  xr2 = xl2 + (size_t)N * C2;               // N*40
    ushort* xlb = (ushort*)(xr2 + (size_t)N * C2);    // N*128 bf16
    ushort* Wt2 = xlb + (size_t)N * H1;               // 64*256*8 bf16
    int* rowptr = (int*)(Wt2 + 64 * 256 * 8);         // N+1
    int* fillp  = rowptr + (N + 1);                   // N
    int* csr    = fillp + N;                          // E

    hipMemsetAsync(rowptr, 0, sizeof(int) * (size_t)(2 * N + 1), stream);
    count_k<<<(E + 255) / 256, 256, 0, stream>>>(dst, rowptr, E);
    scan_k<<<1, 1024, 0, stream>>>(rowptr, N + 1);
    fill_k<<<(E + 255) / 256, 256, 0, stream>>>(src, dst, rowptr, fillp, csr, E);

    prep_k<<<512, 256, 0, stream>>>(W1l, W1r, Wt2);
    gemm1_k<<<(N + 63) / 64, 256, 0, stream>>>(x, Wt2, b1l, b1r, xlb, xr1, N);
    edge1_k<<<(N + 3) / 4, 256, 0, stream>>>(xlb, xr1, rowptr, csr, a1, bias1, /*h=*/xr1, N);
    gemm2_k<<<(N + 3) / 4, 320, 0, stream>>>(xr1, W2l, b2l, W2r, b2r, xl2, xr2, N);
    edge2_k<<<(N + 3) / 4, 256, 0, stream>>>(xl2, xr2, rowptr, csr, a2, bias2, (float*)d_out, N);
}

// Round 3
// 419.322 us; speedup vs baseline: 1.5709x; 1.2242x over previous
//
#include <hip/hip_runtime.h>
#include <math.h>

#define FIN 512
#define H1 128
#define C2 40
#define C2P 64   // padded width for layer-2 gather table

typedef __attribute__((ext_vector_type(8))) short short8;
typedef __attribute__((ext_vector_type(4))) float f32x4;

__device__ __forceinline__ ushort f2bf(float f) {
    union { float f; unsigned u; } c; c.f = f;
    unsigned u = c.u;
    return (ushort)((u + 0x7fffu + ((u >> 16) & 1u)) >> 16);   // RNE
}
__device__ __forceinline__ float bf2f_lo(unsigned u) { return __uint_as_float(u << 16); }
__device__ __forceinline__ float bf2f_hi(unsigned u) { return __uint_as_float(u & 0xffff0000u); }

// ---------------- CSR build ----------------
__global__ void count_k(const int* __restrict__ dst, int* __restrict__ cnt, int E) {
    int e = blockIdx.x * 256 + threadIdx.x;
    if (e < E) atomicAdd(&cnt[dst[e] + 1], 1);
}

__global__ __launch_bounds__(1024) void scan_k(int* __restrict__ arr, int ntot) {
    __shared__ int part[1024];
    int t = threadIdx.x;
    int chunk = (ntot + 1023) / 1024;
    int b = t * chunk;
    int e = b + chunk; if (e > ntot) e = ntot;
    int s = 0;
    for (int j = b; j < e; j++) s += arr[j];
    part[t] = s;
    __syncthreads();
    for (int off = 1; off < 1024; off <<= 1) {
        int v = (t >= off) ? part[t - off] : 0;
        __syncthreads();
        part[t] += v;
        __syncthreads();
    }
    int run = (t == 0) ? 0 : part[t - 1];
    for (int j = b; j < e; j++) { run += arr[j]; arr[j] = run; }
}

__global__ void fill_k(const int* __restrict__ src, const int* __restrict__ dst,
                       const int* __restrict__ rowptr, int* __restrict__ fillp,
                       int* __restrict__ csr, int E) {
    int e = blockIdx.x * 256 + threadIdx.x;
    if (e < E) {
        int d = dst[e];
        int p = atomicAdd(&fillp[d], 1);
        csr[rowptr[d] + p] = src[e];
    }
}

// ---------------- W1 preconvert: Wt2[kc][col][j] = bf16(W[kc*8+j][col]) ----------------
__global__ void prep_k(const float* __restrict__ W1l, const float* __restrict__ W1r,
                       ushort* __restrict__ Wt2) {
    int idx = blockIdx.x * 256 + threadIdx.x;   // 64*256*8 = 131072
    int kc  = idx >> 11;
    int rem = idx & 2047;
    int col = rem >> 3;
    int j   = rem & 7;
    int k   = kc * 8 + j;
    float v = (col < H1) ? W1l[k * H1 + col] : W1r[k * H1 + (col - H1)];
    Wt2[idx] = f2bf(v);
}

// ---------------- GEMM1 (MFMA bf16): x[N,512] @ [W1l|W1r] -> xlb (bf16), xr (f32) ----------
__global__ __launch_bounds__(256) void gemm1_k(
    const float* __restrict__ x, const ushort* __restrict__ Wt2,
    const float* __restrict__ bl, const float* __restrict__ br,
    ushort* __restrict__ xlb, float* __restrict__ xr, int n)
{
    __shared__ ushort As[64][40];
    __shared__ ushort Bs[256][36];

    const int tid = threadIdx.x;
    const int r0  = blockIdx.x * 64;
    const int w    = tid >> 6;
    const int lane = tid & 63;
    const int l15  = lane & 15;
    const int lhi  = lane >> 4;

    f32x4 acc[4][4];
#pragma unroll
    for (int m = 0; m < 4; m++)
#pragma unroll
        for (int nn = 0; nn < 4; nn++) acc[m][nn] = (f32x4){0.f, 0.f, 0.f, 0.f};

    const int arow = tid >> 2;
    const int akc  = (tid & 3) * 8;
    const int arow_g = min(r0 + arow, n - 1);
    const float* aptr = x + (size_t)arow_g * FIN + akc;

    for (int kk = 0; kk < FIN; kk += 32) {
        float4 v0 = *reinterpret_cast<const float4*>(aptr + kk);
        float4 v1 = *reinterpret_cast<const float4*>(aptr + kk + 4);
        short8 ah;
        ah[0] = (short)f2bf(v0.x); ah[1] = (short)f2bf(v0.y);
        ah[2] = (short)f2bf(v0.z); ah[3] = (short)f2bf(v0.w);
        ah[4] = (short)f2bf(v1.x); ah[5] = (short)f2bf(v1.y);
        ah[6] = (short)f2bf(v1.z); ah[7] = (short)f2bf(v1.w);
        *reinterpret_cast<short8*>(&As[arow][akc]) = ah;

        int kc0 = kk >> 3;
#pragma unroll
        for (int q = 0; q < 4; q++) {
            short8 bh = *reinterpret_cast<const short8*>(&Wt2[(size_t)((kc0 + q) * 256 + tid) * 8]);
            *reinterpret_cast<short8*>(&Bs[tid][q * 8]) = bh;
        }
        __syncthreads();

        short8 af[4], bfr[4];
#pragma unroll
        for (int m = 0; m < 4; m++)
            af[m] = *reinterpret_cast<const short8*>(&As[m * 16 + l15][lhi * 8]);
#pragma unroll
        for (int nn = 0; nn < 4; nn++)
            bfr[nn] = *reinterpret_cast<const short8*>(&Bs[w * 64 + nn * 16 + l15][lhi * 8]);
#pragma unroll
        for (int m = 0; m < 4; m++)
#pragma unroll
            for (int nn = 0; nn < 4; nn++)
                acc[m][nn] = __builtin_amdgcn_mfma_f32_16x16x32_bf16(af[m], bfr[nn], acc[m][nn], 0, 0, 0);
        __syncthreads();
    }

#pragma unroll
    for (int nn = 0; nn < 4; nn++) {
        int col = w * 64 + nn * 16 + l15;
        bool left = (col < H1);
        float bias = left ? bl[col] : br[col - H1];
#pragma unroll
        for (int m = 0; m < 4; m++) {
#pragma unroll
            for (int r = 0; r < 4; r++) {
                int row = r0 + m * 16 + lhi * 4 + r;
                if (row < n) {
                    float v = acc[m][nn][r] + bias;
                    if (left) xlb[(size_t)row * H1 + col] = f2bf(v);
                    else      xr [(size_t)row * H1 + (col - H1)] = v;
                }
            }
        }
    }
}

// ---------------- Edge layer 1: 4 waves/block, 1 dst/wave, 4 edges in flight ----------------
// 16 lanes per edge, 8 features per lane; per-group online softmax, merged at end.
__global__ __launch_bounds__(256) void edge1_k(
    const ushort* __restrict__ xlb, const float* xr,
    const int* __restrict__ rowptr, const int* __restrict__ csr,
    const float* __restrict__ att, const float* __restrict__ bias,
    float* h, int n)
{
    int wid  = threadIdx.x >> 6;
    int lane = threadIdx.x & 63;
    int grp  = lane >> 4;       // 0..3: which edge in flight
    int gl   = lane & 15;       // feature slice gl*8 .. +7
    int i = blockIdx.x * 4 + wid;
    if (i >= n) return;

    const float* xrp = &xr[(size_t)i * H1 + gl * 8];
    float4 xr0 = *reinterpret_cast<const float4*>(xrp);
    float4 xr1v = *reinterpret_cast<const float4*>(xrp + 4);
    float xrv[8] = {xr0.x, xr0.y, xr0.z, xr0.w, xr1v.x, xr1v.y, xr1v.z, xr1v.w};
    float4 a0 = *reinterpret_cast<const float4*>(&att[gl * 8]);
    float4 a1 = *reinterpret_cast<const float4*>(&att[gl * 8 + 4]);
    float av[8] = {a0.x, a0.y, a0.z, a0.w, a1.x, a1.y, a1.z, a1.w};

    int e0 = rowptr[i], e1 = rowptr[i + 1];

    float m = -INFINITY, den = 0.f;
    float acc[8];
#pragma unroll
    for (int f = 0; f < 8; f++) acc[f] = 0.f;

    int e = e0 + grp;
    uint4 u;
    if (e < e1) {
        int s = csr[e];
        u = *reinterpret_cast<const uint4*>(&xlb[(size_t)s * H1 + gl * 8]);
    }
    while (e < e1) {
        uint4 cu = u;
        int en = e + 4;
        if (en < e1) {
            int s2 = csr[en];
            u = *reinterpret_cast<const uint4*>(&xlb[(size_t)s2 * H1 + gl * 8]);
        }
        float xlv[8];
        xlv[0] = bf2f_lo(cu.x); xlv[1] = bf2f_hi(cu.x);
        xlv[2] = bf2f_lo(cu.y); xlv[3] = bf2f_hi(cu.y);
        xlv[4] = bf2f_lo(cu.z); xlv[5] = bf2f_hi(cu.z);
        xlv[6] = bf2f_lo(cu.w); xlv[7] = bf2f_hi(cu.w);
        float p = 0.f;
#pragma unroll
        for (int f = 0; f < 8; f++) {
            float t = xlv[f] + xrv[f];
            t = t > 0.f ? t : 0.2f * t;
            p += t * av[f];
        }
#pragma unroll
        for (int o = 8; o > 0; o >>= 1) p += __shfl_xor(p, o);   // reduce within 16 lanes
        float mn = fmaxf(m, p);
        float sc = __expf(m - mn);
        float wgt = __expf(p - mn);
        den = den * sc + wgt;
#pragma unroll
        for (int f = 0; f < 8; f++) acc[f] = acc[f] * sc + wgt * xlv[f];
        m = mn;
        e = en;
    }

    // merge 4 per-group online-softmax states (lanes differing by 16/32)
    float mstar = m;
    mstar = fmaxf(mstar, __shfl_xor(mstar, 16));
    mstar = fmaxf(mstar, __shfl_xor(mstar, 32));
    float scale = __expf(m - mstar);   // 0 for empty groups (m=-inf)
    den *= scale;
#pragma unroll
    for (int f = 0; f < 8; f++) acc[f] *= scale;
    den += __shfl_xor(den, 16); den += __shfl_xor(den, 32);
#pragma unroll
    for (int f = 0; f < 8; f++) {
        acc[f] += __shfl_xor(acc[f], 16);
        acc[f] += __shfl_xor(acc[f], 32);
    }

    if (grp == 0) {
        float inv = 1.f / den;
        float o[8];
#pragma unroll
        for (int f = 0; f < 8; f++) {
            float v = acc[f] * inv + bias[gl * 8 + f];
            o[f] = v > 0.f ? v : expm1f(v);   // ELU
        }
        float* hp = &h[(size_t)i * H1 + gl * 8];
        *reinterpret_cast<float4*>(hp)     = make_float4(o[0], o[1], o[2], o[3]);
        *reinterpret_cast<float4*>(hp + 4) = make_float4(o[4], o[5], o[6], o[7]);
    }
}

// ---------------- GEMM2: h[N,128] @ {W2l,W2r}[128,40] + b -> xl2b (bf16 padded), xr2 ------
__global__ __launch_bounds__(320) void gemm2_k(
    const float* __restrict__ h,
    const float* __restrict__ Wl, const float* __restrict__ bl,
    const float* __restrict__ Wr, const float* __restrict__ br,
    ushort* __restrict__ xl2b, float* __restrict__ xr2, int n)
{
    __shared__ float hs[4 * H1];
    int r0 = blockIdx.x * 4;
    int tid = threadIdx.x;
    for (int j = tid; j < 4 * H1; j += 320) {
        int row = r0 + (j >> 7);
        hs[j] = row < n ? h[(size_t)row * H1 + (j & 127)] : 0.f;
    }
    // zero the pad columns of xl2b (cols 40..63), 4 rows x 24
    if (tid < 96) {
        int rr = r0 + tid / 24;
        if (rr < n) xl2b[(size_t)rr * C2P + C2 + tid % 24] = 0;
    }
    __syncthreads();
    int r = tid / 80;
    int c = tid % 80;
    const float* W = (c < C2) ? Wl : Wr;
    int cc = (c < C2) ? c : c - C2;
    float acc = 0.f;
#pragma unroll 4
    for (int k = 0; k < H1; k++) acc += hs[r * H1 + k] * W[k * C2 + cc];
    int row = r0 + r;
    if (row < n) {
        if (c < C2) xl2b[(size_t)row * C2P + cc] = f2bf(acc + bl[cc]);
        else        xr2 [(size_t)row * C2  + cc] = acc + br[cc];
    }
}

// ---------------- Edge layer 2: 8 edges in flight (8 lanes x 8 features), fused logsoftmax --
__global__ __launch_bounds__(256) void edge2_k(
    const ushort* __restrict__ xl2b, const float* __restrict__ xr2,
    const int* __restrict__ rowptr, const int* __restrict__ csr,
    const float* __restrict__ att, const float* __restrict__ bias,
    float* __restrict__ out, int n)
{
    int wid  = threadIdx.x >> 6;
    int lane = threadIdx.x & 63;
    int grp  = lane >> 3;       // 0..7: edge in flight
    int gl   = lane & 7;        // feature slice gl*8 .. +7 (real if gl<5)
    int i = blockIdx.x * 4 + wid;
    if (i >= n) return;

    float xrv[8], av[8];
#pragma unroll
    for (int f = 0; f < 8; f++) {
        int idx = gl * 8 + f;
        bool real = idx < C2;
        xrv[f] = real ? xr2[(size_t)i * C2 + idx] : 0.f;
        av[f]  = real ? att[idx] : 0.f;
    }

    int e0 = rowptr[i], e1 = rowptr[i + 1];

    float m = -INFINITY, den = 0.f;
    float acc[8];
#pragma unroll
    for (int f = 0; f < 8; f++) acc[f] = 0.f;

    int e = e0 + grp;
    uint4 u;
    if (e < e1) {
        int s = csr[e];
        u = *reinterpret_cast<const uint4*>(&xl2b[(size_t)s * C2P + gl * 8]);
    }
    while (e < e1) {
        uint4 cu = u;
        int en = e + 8;
        if (en < e1) {
            int s2 = csr[en];
            u = *reinterpret_cast<const uint4*>(&xl2b[(size_t)s2 * C2P + gl * 8]);
        }
        float xlv[8];
        xlv[0] = bf2f_lo(cu.x); xlv[1] = bf2f_hi(cu.x);
        xlv[2] = bf2f_lo(cu.y); xlv[3] = bf2f_hi(cu.y);
        xlv[4] = bf2f_lo(cu.z); xlv[5] = bf2f_hi(cu.z);
        xlv[6] = bf2f_lo(cu.w); xlv[7] = bf2f_hi(cu.w);
        float p = 0.f;
#pragma unroll
        for (int f = 0; f < 8; f++) {
            float t = xlv[f] + xrv[f];
            t = t > 0.f ? t : 0.2f * t;
            p += t * av[f];
        }
#pragma unroll
        for (int o = 4; o > 0; o >>= 1) p += __shfl_xor(p, o);   // reduce within 8 lanes
        float mn = fmaxf(m, p);
        float sc = __expf(m - mn);
        float wgt = __expf(p - mn);
        den = den * sc + wgt;
#pragma unroll
        for (int f = 0; f < 8; f++) acc[f] = acc[f] * sc + wgt * xlv[f];
        m = mn;
        e = en;
    }

    // merge 8 per-group states (lanes differing by 8/16/32)
    float mstar = m;
    mstar = fmaxf(mstar, __shfl_xor(mstar, 8));
    mstar = fmaxf(mstar, __shfl_xor(mstar, 16));
    mstar = fmaxf(mstar, __shfl_xor(mstar, 32));
    float scale = __expf(m - mstar);
    den *= scale;
#pragma unroll
    for (int f = 0; f < 8; f++) acc[f] *= scale;
    den += __shfl_xor(den, 8); den += __shfl_xor(den, 16); den += __shfl_xor(den, 32);
#pragma unroll
    for (int f = 0; f < 8; f++) {
        acc[f] += __shfl_xor(acc[f], 8);
        acc[f] += __shfl_xor(acc[f], 16);
        acc[f] += __shfl_xor(acc[f], 32);
    }

    // all lanes now hold the full aggregate for their feature slice (replicated x8)
    float inv = 1.f / den;
    bool real_lane = gl < 5;   // 40 = 5*8, lanes 0..4 fully real
    float o[8];
#pragma unroll
    for (int f = 0; f < 8; f++) {
        int idx = gl * 8 + f;
        o[f] = acc[f] * inv + (idx < C2 ? bias[idx] : 0.f);
    }

    // log-softmax over 40 classes: local max/sum then 3-shuffle reduce over 8 lanes
    float mv = -INFINITY;
    if (real_lane) {
#pragma unroll
        for (int f = 0; f < 8; f++) mv = fmaxf(mv, o[f]);
    }
    mv = fmaxf(mv, __shfl_xor(mv, 1));
    mv = fmaxf(mv, __shfl_xor(mv, 2));
    mv = fmaxf(mv, __shfl_xor(mv, 4));
    float se = 0.f;
    if (real_lane) {
#pragma unroll
        for (int f = 0; f < 8; f++) se += __expf(o[f] - mv);
    }
    se += __shfl_xor(se, 1); se += __shfl_xor(se, 2); se += __shfl_xor(se, 4);
    float lse = mv + logf(se);

    if (grp == 0 && real_lane) {
        float* op = &out[(size_t)i * C2 + gl * 8];
        *reinterpret_cast<float4*>(op)     = make_float4(o[0], o[1], o[2], o[3]);
        *reinterpret_cast<float4*>(op + 4) = make_float4(o[4], o[5], o[6], o[7]);
        float* lp = &out[(size_t)n * C2 + (size_t)i * C2 + gl * 8];
        *reinterpret_cast<float4*>(lp)     = make_float4(o[0] - lse, o[1] - lse, o[2] - lse, o[3] - lse);
        *reinterpret_cast<float4*>(lp + 4) = make_float4(o[4] - lse, o[5] - lse, o[6] - lse, o[7] - lse);
    }
}

// ---------------------------------------------------------------------------
extern "C" void kernel_launch(void* const* d_in, const int* in_sizes, int n_in,
                              void* d_out, int out_size, void* d_ws, size_t ws_size,
                              hipStream_t stream) {
    const float* x    = (const float*)d_in[0];
    const int*   ei   = (const int*)  d_in[1];
    const float* W1l  = (const float*)d_in[2];
    const float* b1l  = (const float*)d_in[3];
    const float* W1r  = (const float*)d_in[4];
    const float* b1r  = (const float*)d_in[5];
    const float* a1   = (const float*)d_in[6];
    const float* bias1= (const float*)d_in[7];
    const float* W2l  = (const float*)d_in[8];
    const float* b2l  = (const float*)d_in[9];
    const float* W2r  = (const float*)d_in[10];
    const float* b2r  = (const float*)d_in[11];
    const float* a2   = (const float*)d_in[12];
    const float* bias2= (const float*)d_in[13];

    const int N = in_sizes[0] / FIN;
    const int E = in_sizes[1] / 2;
    const int* src = ei;
    const int* dst = ei + E;

    // workspace layout (xl2b aliases xlb: xlb dead after edge1, gemm2 runs after)
    float*  xr1 = (float*)d_ws;                       // N*128 f32 (h aliases after edge1)
    float*  xr2 = xr1 + (size_t)N * H1;               // N*40 f32
    ushort* xlb = (ushort*)(xr2 + (size_t)N * C2);    // N*128 bf16
    ushort* xl2b = xlb;                               // N*64 bf16 (alias)
    ushort* Wt2 = xlb + (size_t)N * H1;               // 64*256*8 bf16
    int* rowptr = (int*)(Wt2 + 64 * 256 * 8);         // N+1
    int* fillp  = rowptr + (N + 1);                   // N
    int* csr    = fillp + N;                          // E

    hipMemsetAsync(rowptr, 0, sizeof(int) * (size_t)(2 * N + 1), stream);
    count_k<<<(E + 255) / 256, 256, 0, stream>>>(dst, rowptr, E);
    scan_k<<<1, 1024, 0, stream>>>(rowptr, N + 1);
    fill_k<<<(E + 255) / 256, 256, 0, stream>>>(src, dst, rowptr, fillp, csr, E);

    prep_k<<<512, 256, 0, stream>>>(W1l, W1r, Wt2);
    gemm1_k<<<(N + 63) / 64, 256, 0, stream>>>(x, Wt2, b1l, b1r, xlb, xr1, N);
    edge1_k<<<(N + 3) / 4, 256, 0, stream>>>(xlb, xr1, rowptr, csr, a1, bias1, /*h=*/xr1, N);
    gemm2_k<<<(N + 3) / 4, 320, 0, stream>>>(xr1, W2l, b2l, W2r, b2r, xl2b, xr2, N);
    edge2_k<<<(N + 3) / 4, 256, 0, stream>>>(xl2b, xr2, rowptr, csr, a2, bias2, (float*)d_out, N);
}

// Round 4
// 296.372 us; speedup vs baseline: 2.2226x; 1.4149x over previous
//
#include <hip/hip_runtime.h>
#include <math.h>

#define FIN 512
#define H1 128
#define C2 40
#define C2P 64   // padded width for layer-2 gather table

typedef __attribute__((ext_vector_type(8))) short short8;
typedef __attribute__((ext_vector_type(4))) float f32x4;

__device__ __forceinline__ ushort f2bf(float f) {
    union { float f; unsigned u; } c; c.f = f;
    unsigned u = c.u;
    return (ushort)((u + 0x7fffu + ((u >> 16) & 1u)) >> 16);   // RNE
}
__device__ __forceinline__ float bf2f_lo(unsigned u) { return __uint_as_float(u << 16); }
__device__ __forceinline__ float bf2f_hi(unsigned u) { return __uint_as_float(u & 0xffff0000u); }

// ---------------- CSR build ----------------
__global__ void count_k(const int* __restrict__ dst, int* __restrict__ cnt, int E) {
    int e = blockIdx.x * 256 + threadIdx.x;
    if (e < E) atomicAdd(&cnt[dst[e] + 1], 1);
}

__global__ __launch_bounds__(1024) void scan_k(int* __restrict__ arr, int ntot) {
    __shared__ int part[1024];
    int t = threadIdx.x;
    int chunk = (((ntot + 1023) / 1024) + 3) & ~3;   // multiple of 4
    int b = t * chunk;
    int s = 0;
    bool full = (b + chunk <= ntot);
    if (full) {
#pragma unroll 4
        for (int j = 0; j < chunk; j += 4) {
            int4 v = *reinterpret_cast<const int4*>(&arr[b + j]);
            s += v.x + v.y + v.z + v.w;
        }
    } else {
        for (int j = b; j < ntot; j++) s += arr[j];
    }
    part[t] = s;
    __syncthreads();
    for (int off = 1; off < 1024; off <<= 1) {
        int v = (t >= off) ? part[t - off] : 0;
        __syncthreads();
        part[t] += v;
        __syncthreads();
    }
    int run = (t == 0) ? 0 : part[t - 1];
    if (full) {
        for (int j = 0; j < chunk; j += 4) {
            int4 v = *reinterpret_cast<const int4*>(&arr[b + j]);
            int r0 = run + v.x, r1 = r0 + v.y, r2 = r1 + v.z, r3 = r2 + v.w;
            *reinterpret_cast<int4*>(&arr[b + j]) = make_int4(r0, r1, r2, r3);
            run = r3;
        }
    } else {
        for (int j = b; j < ntot; j++) { run += arr[j]; arr[j] = run; }
    }
}

__global__ void fill_k(const int* __restrict__ src, const int* __restrict__ dst,
                       const int* __restrict__ rowptr, int* __restrict__ fillp,
                       int* __restrict__ csr, int E) {
    int e = blockIdx.x * 256 + threadIdx.x;
    if (e < E) {
        int d = dst[e];
        int p = atomicAdd(&fillp[d], 1);
        csr[rowptr[d] + p] = src[e];
    }
}

// ---------------- W1 preconvert: Wt2[kc][col][j] = bf16(W[kc*8+j][col]) ----------------
__global__ void prep_k(const float* __restrict__ W1l, const float* __restrict__ W1r,
                       ushort* __restrict__ Wt2) {
    int idx = blockIdx.x * 256 + threadIdx.x;   // 64*256*8 = 131072
    int kc  = idx >> 11;
    int rem = idx & 2047;
    int col = rem >> 3;
    int j   = rem & 7;
    int k   = kc * 8 + j;
    float v = (col < H1) ? W1l[k * H1 + col] : W1r[k * H1 + (col - H1)];
    Wt2[idx] = f2bf(v);
}

// ---------------- W2 preconvert: Ws[col][k] = bf16(W2(k,col)), col<40 => W2l -------------
__global__ void prep2_k(const float* __restrict__ W2l, const float* __restrict__ W2r,
                        ushort* __restrict__ Ws) {
    int idx = blockIdx.x * 256 + threadIdx.x;   // 80*128 = 10240
    if (idx >= 80 * H1) return;
    int col = idx >> 7;
    int k   = idx & 127;
    float v = (col < C2) ? W2l[k * C2 + col] : W2r[k * C2 + (col - C2)];
    Ws[idx] = f2bf(v);
}

// ---------------- GEMM1 (MFMA bf16): x[N,512] @ [W1l|W1r] -> xlb (bf16), xr (f32) ----------
__global__ __launch_bounds__(256) void gemm1_k(
    const float* __restrict__ x, const ushort* __restrict__ Wt2,
    const float* __restrict__ bl, const float* __restrict__ br,
    ushort* __restrict__ xlb, float* __restrict__ xr, int n)
{
    __shared__ ushort As[64][40];
    __shared__ ushort Bs[256][36];

    const int tid = threadIdx.x;
    const int r0  = blockIdx.x * 64;
    const int w    = tid >> 6;
    const int lane = tid & 63;
    const int l15  = lane & 15;
    const int lhi  = lane >> 4;

    f32x4 acc[4][4];
#pragma unroll
    for (int m = 0; m < 4; m++)
#pragma unroll
        for (int nn = 0; nn < 4; nn++) acc[m][nn] = (f32x4){0.f, 0.f, 0.f, 0.f};

    const int arow = tid >> 2;
    const int akc  = (tid & 3) * 8;
    const int arow_g = min(r0 + arow, n - 1);
    const float* aptr = x + (size_t)arow_g * FIN + akc;

    for (int kk = 0; kk < FIN; kk += 32) {
        float4 v0 = *reinterpret_cast<const float4*>(aptr + kk);
        float4 v1 = *reinterpret_cast<const float4*>(aptr + kk + 4);
        short8 ah;
        ah[0] = (short)f2bf(v0.x); ah[1] = (short)f2bf(v0.y);
        ah[2] = (short)f2bf(v0.z); ah[3] = (short)f2bf(v0.w);
        ah[4] = (short)f2bf(v1.x); ah[5] = (short)f2bf(v1.y);
        ah[6] = (short)f2bf(v1.z); ah[7] = (short)f2bf(v1.w);
        *reinterpret_cast<short8*>(&As[arow][akc]) = ah;

        int kc0 = kk >> 3;
#pragma unroll
        for (int q = 0; q < 4; q++) {
            short8 bh = *reinterpret_cast<const short8*>(&Wt2[(size_t)((kc0 + q) * 256 + tid) * 8]);
            *reinterpret_cast<short8*>(&Bs[tid][q * 8]) = bh;
        }
        __syncthreads();

        short8 af[4], bfr[4];
#pragma unroll
        for (int m = 0; m < 4; m++)
            af[m] = *reinterpret_cast<const short8*>(&As[m * 16 + l15][lhi * 8]);
#pragma unroll
        for (int nn = 0; nn < 4; nn++)
            bfr[nn] = *reinterpret_cast<const short8*>(&Bs[w * 64 + nn * 16 + l15][lhi * 8]);
#pragma unroll
        for (int m = 0; m < 4; m++)
#pragma unroll
            for (int nn = 0; nn < 4; nn++)
                acc[m][nn] = __builtin_amdgcn_mfma_f32_16x16x32_bf16(af[m], bfr[nn], acc[m][nn], 0, 0, 0);
        __syncthreads();
    }

#pragma unroll
    for (int nn = 0; nn < 4; nn++) {
        int col = w * 64 + nn * 16 + l15;
        bool left = (col < H1);
        float bias = left ? bl[col] : br[col - H1];
#pragma unroll
        for (int m = 0; m < 4; m++) {
#pragma unroll
            for (int r = 0; r < 4; r++) {
                int row = r0 + m * 16 + lhi * 4 + r;
                if (row < n) {
                    float v = acc[m][nn][r] + bias;
                    if (left) xlb[(size_t)row * H1 + col] = f2bf(v);
                    else      xr [(size_t)row * H1 + (col - H1)] = v;
                }
            }
        }
    }
}

// ---------------- Edge layer 1: 4 waves/block, 1 dst/wave, 4 edges in flight ----------------
__global__ __launch_bounds__(256) void edge1_k(
    const ushort* __restrict__ xlb, const float* xr,
    const int* __restrict__ rowptr, const int* __restrict__ csr,
    const float* __restrict__ att, const float* __restrict__ bias,
    float* h, int n)
{
    int wid  = threadIdx.x >> 6;
    int lane = threadIdx.x & 63;
    int grp  = lane >> 4;       // 0..3: which edge in flight
    int gl   = lane & 15;       // feature slice gl*8 .. +7
    int i = blockIdx.x * 4 + wid;
    if (i >= n) return;

    const float* xrp = &xr[(size_t)i * H1 + gl * 8];
    float4 xr0 = *reinterpret_cast<const float4*>(xrp);
    float4 xr1v = *reinterpret_cast<const float4*>(xrp + 4);
    float xrv[8] = {xr0.x, xr0.y, xr0.z, xr0.w, xr1v.x, xr1v.y, xr1v.z, xr1v.w};
    float4 a0 = *reinterpret_cast<const float4*>(&att[gl * 8]);
    float4 a1 = *reinterpret_cast<const float4*>(&att[gl * 8 + 4]);
    float av[8] = {a0.x, a0.y, a0.z, a0.w, a1.x, a1.y, a1.z, a1.w};

    int e0 = rowptr[i], e1 = rowptr[i + 1];

    float m = -INFINITY, den = 0.f;
    float acc[8];
#pragma unroll
    for (int f = 0; f < 8; f++) acc[f] = 0.f;

    int e = e0 + grp;
    uint4 u;
    if (e < e1) {
        int s = csr[e];
        u = *reinterpret_cast<const uint4*>(&xlb[(size_t)s * H1 + gl * 8]);
    }
    while (e < e1) {
        uint4 cu = u;
        int en = e + 4;
        if (en < e1) {
            int s2 = csr[en];
            u = *reinterpret_cast<const uint4*>(&xlb[(size_t)s2 * H1 + gl * 8]);
        }
        float xlv[8];
        xlv[0] = bf2f_lo(cu.x); xlv[1] = bf2f_hi(cu.x);
        xlv[2] = bf2f_lo(cu.y); xlv[3] = bf2f_hi(cu.y);
        xlv[4] = bf2f_lo(cu.z); xlv[5] = bf2f_hi(cu.z);
        xlv[6] = bf2f_lo(cu.w); xlv[7] = bf2f_hi(cu.w);
        float p = 0.f;
#pragma unroll
        for (int f = 0; f < 8; f++) {
            float t = xlv[f] + xrv[f];
            t = t > 0.f ? t : 0.2f * t;
            p += t * av[f];
        }
#pragma unroll
        for (int o = 8; o > 0; o >>= 1) p += __shfl_xor(p, o);   // reduce within 16 lanes
        float mn = fmaxf(m, p);
        float sc = __expf(m - mn);
        float wgt = __expf(p - mn);
        den = den * sc + wgt;
#pragma unroll
        for (int f = 0; f < 8; f++) acc[f] = acc[f] * sc + wgt * xlv[f];
        m = mn;
        e = en;
    }

    // merge 4 per-group online-softmax states (lanes differing by 16/32)
    float mstar = m;
    mstar = fmaxf(mstar, __shfl_xor(mstar, 16));
    mstar = fmaxf(mstar, __shfl_xor(mstar, 32));
    float scale = __expf(m - mstar);   // 0 for empty groups (m=-inf)
    den *= scale;
#pragma unroll
    for (int f = 0; f < 8; f++) acc[f] *= scale;
    den += __shfl_xor(den, 16); den += __shfl_xor(den, 32);
#pragma unroll
    for (int f = 0; f < 8; f++) {
        acc[f] += __shfl_xor(acc[f], 16);
        acc[f] += __shfl_xor(acc[f], 32);
    }

    if (grp == 0) {
        float inv = 1.f / den;
        float o[8];
#pragma unroll
        for (int f = 0; f < 8; f++) {
            float v = acc[f] * inv + bias[gl * 8 + f];
            o[f] = v > 0.f ? v : expm1f(v);   // ELU
        }
        float* hp = &h[(size_t)i * H1 + gl * 8];
        *reinterpret_cast<float4*>(hp)     = make_float4(o[0], o[1], o[2], o[3]);
        *reinterpret_cast<float4*>(hp + 4) = make_float4(o[4], o[5], o[6], o[7]);
    }
}

// ---------------- GEMM2 (MFMA): h[N,128] f32 @ Ws[80][128] -> xl2b bf16 (+pad), xr2 f32 ----
// 4 waves x 16 rows = 64 rows per block; 5 col-frags x 4 k-chunks = 20 MFMA per wave.
__global__ __launch_bounds__(256) void gemm2_k(
    const float* __restrict__ h, const ushort* __restrict__ Ws,
    const float* __restrict__ bl, const float* __restrict__ br,
    ushort* __restrict__ xl2b, float* __restrict__ xr2, int n)
{
    __shared__ ushort WsL[80][136];   // [col][k], padded

    const int tid = threadIdx.x;
    const int w    = tid >> 6;
    const int lane = tid & 63;
    const int l15  = lane & 15;
    const int lhi  = lane >> 4;
    const int r0 = blockIdx.x * 64;

    // stage Ws (80x128 bf16) into LDS, 16B chunks
#pragma unroll
    for (int q = 0; q < 5; q++) {
        int c = tid + q * 256;            // 0..1279
        int col = c >> 4;
        int k0  = (c & 15) * 8;
        *reinterpret_cast<short8*>(&WsL[col][k0]) =
            *reinterpret_cast<const short8*>(&Ws[col * H1 + k0]);
    }
    __syncthreads();

    const int arow = min(r0 + w * 16 + l15, n - 1);
    const float* ap = &h[(size_t)arow * H1 + lhi * 8];

    f32x4 acc[5];
#pragma unroll
    for (int nt = 0; nt < 5; nt++) acc[nt] = (f32x4){0.f, 0.f, 0.f, 0.f};

#pragma unroll
    for (int kc = 0; kc < 4; kc++) {
        float4 v0 = *reinterpret_cast<const float4*>(ap + kc * 32);
        float4 v1 = *reinterpret_cast<const float4*>(ap + kc * 32 + 4);
        short8 af;
        af[0] = (short)f2bf(v0.x); af[1] = (short)f2bf(v0.y);
        af[2] = (short)f2bf(v0.z); af[3] = (short)f2bf(v0.w);
        af[4] = (short)f2bf(v1.x); af[5] = (short)f2bf(v1.y);
        af[6] = (short)f2bf(v1.z); af[7] = (short)f2bf(v1.w);
#pragma unroll
        for (int nt = 0; nt < 5; nt++) {
            short8 bf = *reinterpret_cast<const short8*>(&WsL[nt * 16 + l15][kc * 32 + lhi * 8]);
            acc[nt] = __builtin_amdgcn_mfma_f32_16x16x32_bf16(af, bf, acc[nt], 0, 0, 0);
        }
    }

    // epilogue: col = nt*16 + l15, row = r0 + w*16 + lhi*4 + r
#pragma unroll
    for (int nt = 0; nt < 5; nt++) {
        int col = nt * 16 + l15;
        float bias = (col < C2) ? bl[col] : br[col - C2];
#pragma unroll
        for (int r = 0; r < 4; r++) {
            int row = r0 + w * 16 + lhi * 4 + r;
            if (row < n) {
                float v = acc[nt][r] + bias;
                if (col < C2) xl2b[(size_t)row * C2P + col] = f2bf(v);
                else          xr2 [(size_t)row * C2  + (col - C2)] = v;
            }
        }
    }
    // zero pad cols 40..63 of xl2b (48B per row = 3 x 16B)
    {
        int row = r0 + w * 16 + l15;
        int part = lhi;   // 0..3, use 0..2
        if (part < 3 && row < n) {
            uint4 z = make_uint4(0u, 0u, 0u, 0u);
            *reinterpret_cast<uint4*>(&xl2b[(size_t)row * C2P + C2 + part * 8]) = z;
        }
    }
}

// ---------------- Edge layer 2: 8 edges in flight (8 lanes x 8 features), fused logsoftmax --
__global__ __launch_bounds__(256) void edge2_k(
    const ushort* __restrict__ xl2b, const float* __restrict__ xr2,
    const int* __restrict__ rowptr, const int* __restrict__ csr,
    const float* __restrict__ att, const float* __restrict__ bias,
    float* __restrict__ out, int n)
{
    int wid  = threadIdx.x >> 6;
    int lane = threadIdx.x & 63;
    int grp  = lane >> 3;       // 0..7: edge in flight
    int gl   = lane & 7;        // feature slice gl*8 .. +7 (real if gl<5)
    int i = blockIdx.x * 4 + wid;
    if (i >= n) return;

    float xrv[8], av[8];
#pragma unroll
    for (int f = 0; f < 8; f++) {
        int idx = gl * 8 + f;
        bool real = idx < C2;
        xrv[f] = real ? xr2[(size_t)i * C2 + idx] : 0.f;
        av[f]  = real ? att[idx] : 0.f;
    }

    int e0 = rowptr[i], e1 = rowptr[i + 1];

    float m = -INFINITY, den = 0.f;
    float acc[8];
#pragma unroll
    for (int f = 0; f < 8; f++) acc[f] = 0.f;

    int e = e0 + grp;
    uint4 u;
    if (e < e1) {
        int s = csr[e];
        u = *reinterpret_cast<const uint4*>(&xl2b[(size_t)s * C2P + gl * 8]);
    }
    while (e < e1) {
        uint4 cu = u;
        int en = e + 8;
        if (en < e1) {
            int s2 = csr[en];
            u = *reinterpret_cast<const uint4*>(&xl2b[(size_t)s2 * C2P + gl * 8]);
        }
        float xlv[8];
        xlv[0] = bf2f_lo(cu.x); xlv[1] = bf2f_hi(cu.x);
        xlv[2] = bf2f_lo(cu.y); xlv[3] = bf2f_hi(cu.y);
        xlv[4] = bf2f_lo(cu.z); xlv[5] = bf2f_hi(cu.z);
        xlv[6] = bf2f_lo(cu.w); xlv[7] = bf2f_hi(cu.w);
        float p = 0.f;
#pragma unroll
        for (int f = 0; f < 8; f++) {
            float t = xlv[f] + xrv[f];
            t = t > 0.f ? t : 0.2f * t;
            p += t * av[f];
        }
#pragma unroll
        for (int o = 4; o > 0; o >>= 1) p += __shfl_xor(p, o);   // reduce within 8 lanes
        float mn = fmaxf(m, p);
        float sc = __expf(m - mn);
        float wgt = __expf(p - mn);
        den = den * sc + wgt;
#pragma unroll
        for (int f = 0; f < 8; f++) acc[f] = acc[f] * sc + wgt * xlv[f];
        m = mn;
        e = en;
    }

    // merge 8 per-group states
    float mstar = m;
    mstar = fmaxf(mstar, __shfl_xor(mstar, 8));
    mstar = fmaxf(mstar, __shfl_xor(mstar, 16));
    mstar = fmaxf(mstar, __shfl_xor(mstar, 32));
    float scale = __expf(m - mstar);
    den *= scale;
#pragma unroll
    for (int f = 0; f < 8; f++) acc[f] *= scale;
    den += __shfl_xor(den, 8); den += __shfl_xor(den, 16); den += __shfl_xor(den, 32);
#pragma unroll
    for (int f = 0; f < 8; f++) {
        acc[f] += __shfl_xor(acc[f], 8);
        acc[f] += __shfl_xor(acc[f], 16);
        acc[f] += __shfl_xor(acc[f], 32);
    }

    float inv = 1.f / den;
    bool real_lane = gl < 5;
    float o[8];
#pragma unroll
    for (int f = 0; f < 8; f++) {
        int idx = gl * 8 + f;
        o[f] = acc[f] * inv + (idx < C2 ? bias[idx] : 0.f);
    }

    float mv = -INFINITY;
    if (real_lane) {
#pragma unroll
        for (int f = 0; f < 8; f++) mv = fmaxf(mv, o[f]);
    }
    mv = fmaxf(mv, __shfl_xor(mv, 1));
    mv = fmaxf(mv, __shfl_xor(mv, 2));
    mv = fmaxf(mv, __shfl_xor(mv, 4));
    float se = 0.f;
    if (real_lane) {
#pragma unroll
        for (int f = 0; f < 8; f++) se += __expf(o[f] - mv);
    }
    se += __shfl_xor(se, 1); se += __shfl_xor(se, 2); se += __shfl_xor(se, 4);
    float lse = mv + logf(se);

    if (grp == 0 && real_lane) {
        float* op = &out[(size_t)i * C2 + gl * 8];
        *reinterpret_cast<float4*>(op)     = make_float4(o[0], o[1], o[2], o[3]);
        *reinterpret_cast<float4*>(op + 4) = make_float4(o[4], o[5], o[6], o[7]);
        float* lp = &out[(size_t)n * C2 + (size_t)i * C2 + gl * 8];
        *reinterpret_cast<float4*>(lp)     = make_float4(o[0] - lse, o[1] - lse, o[2] - lse, o[3] - lse);
        *reinterpret_cast<float4*>(lp + 4) = make_float4(o[4] - lse, o[5] - lse, o[6] - lse, o[7] - lse);
    }
}

// ---------------------------------------------------------------------------
extern "C" void kernel_launch(void* const* d_in, const int* in_sizes, int n_in,
                              void* d_out, int out_size, void* d_ws, size_t ws_size,
                              hipStream_t stream) {
    const float* x    = (const float*)d_in[0];
    const int*   ei   = (const int*)  d_in[1];
    const float* W1l  = (const float*)d_in[2];
    const float* b1l  = (const float*)d_in[3];
    const float* W1r  = (const float*)d_in[4];
    const float* b1r  = (const float*)d_in[5];
    const float* a1   = (const float*)d_in[6];
    const float* bias1= (const float*)d_in[7];
    const float* W2l  = (const float*)d_in[8];
    const float* b2l  = (const float*)d_in[9];
    const float* W2r  = (const float*)d_in[10];
    const float* b2r  = (const float*)d_in[11];
    const float* a2   = (const float*)d_in[12];
    const float* bias2= (const float*)d_in[13];

    const int N = in_sizes[0] / FIN;
    const int E = in_sizes[1] / 2;
    const int* src = ei;
    const int* dst = ei + E;

    // workspace layout (xl2b aliases xlb: xlb dead after edge1, gemm2 runs after)
    float*  xr1 = (float*)d_ws;                       // N*128 f32 (h aliases after edge1)
    float*  xr2 = xr1 + (size_t)N * H1;               // N*40 f32
    ushort* xlb = (ushort*)(xr2 + (size_t)N * C2);    // N*128 bf16
    ushort* xl2b = xlb;                               // N*64 bf16 (alias)
    ushort* Wt2 = xlb + (size_t)N * H1;               // 131072 bf16
    ushort* Ws2 = Wt2 + 131072;                       // 10240 bf16
    int* rowptr = (int*)(Ws2 + 10240);                // N+1
    int* fillp  = rowptr + (N + 1);                   // N
    int* csr    = fillp + N;                          // E

    hipMemsetAsync(rowptr, 0, sizeof(int) * (size_t)(2 * N + 1), stream);
    count_k<<<(E + 255) / 256, 256, 0, stream>>>(dst, rowptr, E);
    scan_k<<<1, 1024, 0, stream>>>(rowptr, N + 1);
    fill_k<<<(E + 255) / 256, 256, 0, stream>>>(src, dst, rowptr, fillp, csr, E);

    prep_k<<<512, 256, 0, stream>>>(W1l, W1r, Wt2);
    prep2_k<<<40, 256, 0, stream>>>(W2l, W2r, Ws2);
    gemm1_k<<<(N + 63) / 64, 256, 0, stream>>>(x, Wt2, b1l, b1r, xlb, xr1, N);
    edge1_k<<<(N + 3) / 4, 256, 0, stream>>>(xlb, xr1, rowptr, csr, a1, bias1, /*h=*/xr1, N);
    gemm2_k<<<(N + 63) / 64, 256, 0, stream>>>(xr1, Ws2, b2l, b2r, xl2b, xr2, N);
    edge2_k<<<(N + 3) / 4, 256, 0, stream>>>(xl2b, xr2, rowptr, csr, a2, bias2, (float*)d_out, N);
}